// Round 1
// baseline (1391.968 us; speedup 1.0000x reference)
//
#include <hip/hip_runtime.h>

#define N_TOK 8192
#define DM 1024
#define HID 4096
#define NE 8
#define MAX_TILES 136
#define MAX_SLOTS (MAX_TILES * 128)
#define LN_EPS 1e-5f

typedef __attribute__((ext_vector_type(8))) _Float16 f16x8;
typedef __attribute__((ext_vector_type(4))) _Float16 f16x4;
typedef __attribute__((ext_vector_type(4))) float f32x4;

// ---------------- workspace layout ----------------
constexpr size_t OFF_WT1 = 0;                                       // [E][HID][DM] f16
constexpr size_t OFF_WT2 = OFF_WT1 + (size_t)NE * HID * DM * 2;     // [E][DM][HID] f16
constexpr size_t OFF_XG  = OFF_WT2 + (size_t)NE * DM * HID * 2;     // [MAX_SLOTS][DM] f16
constexpr size_t OFF_H   = OFF_XG + (size_t)MAX_SLOTS * DM * 2;     // [MAX_SLOTS][HID] f16
constexpr size_t OFF_MIX = OFF_H + (size_t)MAX_SLOTS * HID * 2;     // [N_TOK][DM] f32
constexpr size_t OFF_TOPI = OFF_MIX + (size_t)N_TOK * DM * 4;       // [N_TOK][2] i32
constexpr size_t OFF_TOPG = OFF_TOPI + (size_t)N_TOK * 2 * 4;       // [N_TOK][2] f32
constexpr size_t OFF_PTOK = OFF_TOPG + (size_t)N_TOK * 2 * 4;       // [MAX_SLOTS] i32
constexpr size_t OFF_PGATE = OFF_PTOK + (size_t)MAX_SLOTS * 4;      // [MAX_SLOTS] f32
constexpr size_t OFF_HDR = OFF_PGATE + (size_t)MAX_SLOTS * 4;       // header ints/floats
constexpr size_t WS_NEEDED = OFF_HDR + 4096;
// header: [0..7] cnt, [8..15] imp(float), [16..23] cursor, [24..32] off,
//         [33] n_tiles, [34..169] tile_expert

__device__ inline float gelu_tanh(float v) {
  float c = 0.7978845608028654f * (v + 0.044715f * v * v * v);
  return 0.5f * v * (1.0f + tanhf(c));
}

// ---------------- router: fp64 logits, top-2, softmax stats ----------------
__global__ __launch_bounds__(256) void k_router(
    const float* __restrict__ x, const float* __restrict__ Wr,
    int* __restrict__ topi, float* __restrict__ topg,
    int* __restrict__ cnt, float* __restrict__ imp) {
  __shared__ float wr[DM * NE];          // 32 KB
  __shared__ float blkImp[NE];
  __shared__ int blkCnt[NE];
  int tid = threadIdx.x;
  if (tid < NE) { blkImp[tid] = 0.0f; blkCnt[tid] = 0; }
  for (int i = tid; i < DM * NE / 4; i += 256)
    ((float4*)wr)[i] = ((const float4*)Wr)[i];
  __syncthreads();
  int wave = tid >> 6, lane = tid & 63;
  for (int it = 0; it < 4; ++it) {
    int t = blockIdx.x * 16 + wave * 4 + it;
    double acc[NE];
#pragma unroll
    for (int e = 0; e < NE; ++e) acc[e] = 0.0;
    for (int j = 0; j < DM / 64; ++j) {
      int d = j * 64 + lane;
      float xv = x[(size_t)t * DM + d];
#pragma unroll
      for (int e = 0; e < NE; ++e) acc[e] += (double)xv * (double)wr[d * NE + e];
    }
#pragma unroll
    for (int off = 32; off > 0; off >>= 1) {
#pragma unroll
      for (int e = 0; e < NE; ++e) acc[e] += __shfl_down(acc[e], off);
    }
    if (lane == 0) {
      int i0 = 0;
#pragma unroll
      for (int e = 1; e < NE; ++e) if (acc[e] > acc[i0]) i0 = e;
      int i1 = (i0 == 0) ? 1 : 0;
#pragma unroll
      for (int e = 0; e < NE; ++e) if (e != i0 && acc[e] > acc[i1]) i1 = e;
      double g0 = 1.0 / (1.0 + exp(acc[i1] - acc[i0]));
      topi[t * 2] = i0; topi[t * 2 + 1] = i1;
      topg[t * 2] = (float)g0; topg[t * 2 + 1] = (float)(1.0 - g0);
      atomicAdd(&blkCnt[i0], 1); atomicAdd(&blkCnt[i1], 1);
      double mx = acc[0];
#pragma unroll
      for (int e = 1; e < NE; ++e) mx = acc[e] > mx ? acc[e] : mx;
      double s = 0.0, p[NE];
#pragma unroll
      for (int e = 0; e < NE; ++e) { p[e] = exp(acc[e] - mx); s += p[e]; }
      double inv = 1.0 / s;
#pragma unroll
      for (int e = 0; e < NE; ++e) atomicAdd(&blkImp[e], (float)(p[e] * inv));
    }
  }
  __syncthreads();
  if (tid < NE) { atomicAdd(&cnt[tid], blkCnt[tid]); atomicAdd(&imp[tid], blkImp[tid]); }
}

// ---------------- setup: offsets (128-aligned), tile map, aux loss ----------------
__global__ void k_setup(int* __restrict__ hdr, float* __restrict__ aux_out) {
  int* cnt = hdr;
  float* imp = (float*)(hdr + 8);
  int* cursor = hdr + 16;
  int* off = hdr + 24;
  int* n_tiles_p = hdr + 33;
  int* tile_expert = hdr + 34;
  int* pair_token = nullptr;  // set below via offset math not needed here
  (void)pair_token;
  if (threadIdx.x == 0) {
    int offl[NE + 1];
    int o = 0;
    for (int e = 0; e < NE; ++e) {
      offl[e] = o; off[e] = o; cursor[e] = o;
      o += ((cnt[e] + 127) >> 7) << 7;
    }
    offl[NE] = o; off[NE] = o;
    int nt = o >> 7;
    *n_tiles_p = nt;
    int e = 0;
    for (int i = 0; i < nt; ++i) {
      while (i * 128 >= offl[e + 1]) ++e;
      tile_expert[i] = e;
    }
    double a = 0.0;
    for (int e2 = 0; e2 < NE; ++e2)
      a += ((double)imp[e2] / (double)N_TOK) * ((double)cnt[e2] / (double)N_TOK);
    *aux_out = (float)((double)NE * a);
  }
}

__global__ __launch_bounds__(256) void k_init_pairs(int* __restrict__ pair_token) {
  int i = blockIdx.x * 256 + threadIdx.x;
  if (i < MAX_SLOTS) pair_token[i] = -1;
}

// ---------------- scatter token->slot ----------------
__global__ __launch_bounds__(256) void k_scatter(
    const int* __restrict__ topi, const float* __restrict__ topg,
    int* __restrict__ cursor, int* __restrict__ pair_token,
    float* __restrict__ pair_gate) {
  int t = blockIdx.x * 256 + threadIdx.x;
#pragma unroll
  for (int k = 0; k < 2; ++k) {
    int e = topi[t * 2 + k];
    int p = atomicAdd(&cursor[e], 1);
    pair_token[p] = t;
    pair_gate[p] = topg[t * 2 + k];
  }
}

// ---------------- gather x rows (fp32 -> f16) ----------------
__global__ __launch_bounds__(256) void k_gather(
    const float* __restrict__ x, const int* __restrict__ pair_token,
    _Float16* __restrict__ Xg) {
  int slot = blockIdx.x;
  int t = pair_token[slot];
  int d = threadIdx.x * 4;
  f16x4 v4 = {0, 0, 0, 0};
  if (t >= 0) {
    float4 v = *(const float4*)(x + (size_t)t * DM + d);
    v4[0] = (_Float16)v.x; v4[1] = (_Float16)v.y;
    v4[2] = (_Float16)v.z; v4[3] = (_Float16)v.w;
  }
  *(f16x4*)(Xg + (size_t)slot * DM + d) = v4;
}

// ---------------- transpose + cast weights: in fp32 [R][C] -> out f16 [C][R] ----------------
__global__ __launch_bounds__(256) void k_transpose(
    const float* __restrict__ in, _Float16* __restrict__ out, int R, int C) {
  __shared__ float tile[32][33];
  size_t base = (size_t)blockIdx.z * R * C;
  const float* src = in + base;
  _Float16* dst = out + base;
  int c0 = blockIdx.x * 32, r0 = blockIdx.y * 32;
  int tx = threadIdx.x & 31, ty = threadIdx.x >> 5;
#pragma unroll
  for (int i = 0; i < 32; i += 8)
    tile[ty + i][tx] = src[(size_t)(r0 + ty + i) * C + c0 + tx];
  __syncthreads();
#pragma unroll
  for (int i = 0; i < 32; i += 8)
    dst[(size_t)(c0 + ty + i) * R + r0 + tx] = (_Float16)tile[tx][ty + i];
}

// ---------------- GEMM staging: 128 rows x 64 k (f16) into LDS with +8 pad ----------------
__device__ inline void stage128x64(const _Float16* __restrict__ g, int ld,
                                   _Float16* __restrict__ l, int tid) {
  int r = tid >> 3, c = (tid & 7) * 8;
#pragma unroll
  for (int p = 0; p < 4; ++p) {
    int row = p * 32 + r;
    *(f16x8*)(l + row * 72 + c) = *(const f16x8*)(g + (size_t)row * ld + c);
  }
}

// ---------------- GEMM1: H = gelu(Xg @ W1[e] + b1[e]) ----------------
__global__ __launch_bounds__(256, 2) void k_gemm1(
    const _Float16* __restrict__ Xg, const _Float16* __restrict__ Wt1,
    const float* __restrict__ b1, _Float16* __restrict__ H,
    const int* __restrict__ hdr) {
  int tileM = blockIdx.y;
  if (tileM >= hdr[33]) return;
  int e = hdr[34 + tileM];
  int tileN = blockIdx.x;
  __shared__ _Float16 Al[128 * 72];
  __shared__ _Float16 Bl[128 * 72];
  int tid = threadIdx.x;
  const _Float16* Ag = Xg + (size_t)tileM * 128 * DM;
  const _Float16* Bg = Wt1 + (size_t)e * HID * DM + (size_t)tileN * 128 * DM;
  f32x4 acc[4][4];
  const f32x4 fz = {0.f, 0.f, 0.f, 0.f};
#pragma unroll
  for (int a = 0; a < 4; ++a)
#pragma unroll
    for (int b = 0; b < 4; ++b) acc[a][b] = fz;
  int wave = tid >> 6, lane = tid & 63;
  int wm = wave & 1, wn = wave >> 1;
  int l16 = lane & 15, quad = lane >> 4;
  for (int k0 = 0; k0 < DM; k0 += 64) {
    stage128x64(Ag + k0, DM, Al, tid);
    stage128x64(Bg + k0, DM, Bl, tid);
    __syncthreads();
#pragma unroll
    for (int kk = 0; kk < 64; kk += 32) {
      f16x8 af[4], bfr[4];
#pragma unroll
      for (int mi = 0; mi < 4; ++mi)
        af[mi] = *(const f16x8*)(Al + (wm * 64 + mi * 16 + l16) * 72 + kk + quad * 8);
#pragma unroll
      for (int ni = 0; ni < 4; ++ni)
        bfr[ni] = *(const f16x8*)(Bl + (wn * 64 + ni * 16 + l16) * 72 + kk + quad * 8);
#pragma unroll
      for (int mi = 0; mi < 4; ++mi)
#pragma unroll
        for (int ni = 0; ni < 4; ++ni)
          acc[mi][ni] = __builtin_amdgcn_mfma_f32_16x16x32_f16(af[mi], bfr[ni], acc[mi][ni], 0, 0, 0);
    }
    __syncthreads();
  }
  int rowBase = tileM * 128 + wm * 64;
  int colBase = tileN * 128 + wn * 64;
#pragma unroll
  for (int ni = 0; ni < 4; ++ni) {
    int col = colBase + ni * 16 + l16;
    float bv = b1[e * HID + col];
#pragma unroll
    for (int mi = 0; mi < 4; ++mi)
#pragma unroll
      for (int i = 0; i < 4; ++i) {
        int row = rowBase + mi * 16 + quad * 4 + i;
        float v = acc[mi][ni][i] + bv;
        H[(size_t)row * HID + col] = (_Float16)gelu_tanh(v);
      }
  }
}

// ---------------- GEMM2: mixed[t] += gate * (H @ W2[e] + b2[e]) ----------------
__global__ __launch_bounds__(256, 2) void k_gemm2(
    const _Float16* __restrict__ H, const _Float16* __restrict__ Wt2,
    const float* __restrict__ b2, const int* __restrict__ pair_token,
    const float* __restrict__ pair_gate, float* __restrict__ mixed,
    const int* __restrict__ hdr) {
  int tileM = blockIdx.y;
  if (tileM >= hdr[33]) return;
  int e = hdr[34 + tileM];
  int tileN = blockIdx.x;
  __shared__ _Float16 Al[128 * 72];
  __shared__ _Float16 Bl[128 * 72];
  int tid = threadIdx.x;
  const _Float16* Ag = H + (size_t)tileM * 128 * HID;
  const _Float16* Bg = Wt2 + (size_t)e * DM * HID + (size_t)tileN * 128 * HID;
  f32x4 acc[4][4];
  const f32x4 fz = {0.f, 0.f, 0.f, 0.f};
#pragma unroll
  for (int a = 0; a < 4; ++a)
#pragma unroll
    for (int b = 0; b < 4; ++b) acc[a][b] = fz;
  int wave = tid >> 6, lane = tid & 63;
  int wm = wave & 1, wn = wave >> 1;
  int l16 = lane & 15, quad = lane >> 4;
  for (int k0 = 0; k0 < HID; k0 += 64) {
    stage128x64(Ag + k0, HID, Al, tid);
    stage128x64(Bg + k0, HID, Bl, tid);
    __syncthreads();
#pragma unroll
    for (int kk = 0; kk < 64; kk += 32) {
      f16x8 af[4], bfr[4];
#pragma unroll
      for (int mi = 0; mi < 4; ++mi)
        af[mi] = *(const f16x8*)(Al + (wm * 64 + mi * 16 + l16) * 72 + kk + quad * 8);
#pragma unroll
      for (int ni = 0; ni < 4; ++ni)
        bfr[ni] = *(const f16x8*)(Bl + (wn * 64 + ni * 16 + l16) * 72 + kk + quad * 8);
#pragma unroll
      for (int mi = 0; mi < 4; ++mi)
#pragma unroll
        for (int ni = 0; ni < 4; ++ni)
          acc[mi][ni] = __builtin_amdgcn_mfma_f32_16x16x32_f16(af[mi], bfr[ni], acc[mi][ni], 0, 0, 0);
    }
    __syncthreads();
  }
  int rowBase = tileM * 128 + wm * 64;
  int colBase = tileN * 128 + wn * 64;
#pragma unroll
  for (int mi = 0; mi < 4; ++mi)
#pragma unroll
    for (int i = 0; i < 4; ++i) {
      int slot = rowBase + mi * 16 + quad * 4 + i;
      int t = pair_token[slot];
      if (t < 0) continue;
      float g = pair_gate[slot];
#pragma unroll
      for (int ni = 0; ni < 4; ++ni) {
        int col = colBase + ni * 16 + l16;
        float v = (acc[mi][ni][i] + b2[e * DM + col]) * g;
        atomicAdd(mixed + (size_t)t * DM + col, v);
      }
    }
}

// ---------------- residual + LayerNorm ----------------
__global__ __launch_bounds__(256) void k_ln(
    const float* __restrict__ x, const float* __restrict__ mixed,
    const float* __restrict__ lnw, const float* __restrict__ lnb,
    float* __restrict__ out) {
  int t = blockIdx.x, tid = threadIdx.x;
  float4 xv = ((const float4*)(x + (size_t)t * DM))[tid];
  float4 mv = ((const float4*)(mixed + (size_t)t * DM))[tid];
  float r0 = xv.x + mv.x, r1 = xv.y + mv.y, r2 = xv.z + mv.z, r3 = xv.w + mv.w;
  float s = r0 + r1 + r2 + r3;
  float s2 = r0 * r0 + r1 * r1 + r2 * r2 + r3 * r3;
#pragma unroll
  for (int off = 32; off > 0; off >>= 1) {
    s += __shfl_down(s, off);
    s2 += __shfl_down(s2, off);
  }
  __shared__ float ss[4], ss2[4];
  int wave = tid >> 6, lane = tid & 63;
  if (lane == 0) { ss[wave] = s; ss2[wave] = s2; }
  __syncthreads();
  float S = ss[0] + ss[1] + ss[2] + ss[3];
  float S2 = ss2[0] + ss2[1] + ss2[2] + ss2[3];
  float mu = S * (1.0f / DM);
  float var = S2 * (1.0f / DM) - mu * mu;
  float inv = rsqrtf(var + LN_EPS);
  float4 wv = ((const float4*)lnw)[tid];
  float4 bv = ((const float4*)lnb)[tid];
  float4 o;
  o.x = (r0 - mu) * inv * wv.x + bv.x;
  o.y = (r1 - mu) * inv * wv.y + bv.y;
  o.z = (r2 - mu) * inv * wv.z + bv.z;
  o.w = (r3 - mu) * inv * wv.w + bv.w;
  ((float4*)(out + (size_t)t * DM))[tid] = o;
}

// sentinel: encodes ws_size (MB) into absmax if workspace is too small
__global__ void k_sentinel(float* out, float v) { out[threadIdx.x] = v; }

extern "C" void kernel_launch(void* const* d_in, const int* in_sizes, int n_in,
                              void* d_out, int out_size, void* d_ws, size_t ws_size,
                              hipStream_t stream) {
  const float* x = (const float*)d_in[0];
  const float* Wr = (const float*)d_in[1];
  const float* W1 = (const float*)d_in[2];
  const float* b1 = (const float*)d_in[3];
  const float* W2 = (const float*)d_in[4];
  const float* b2 = (const float*)d_in[5];
  const float* lnw = (const float*)d_in[6];
  const float* lnb = (const float*)d_in[7];
  float* out = (float*)d_out;
  char* ws = (char*)d_ws;

  if (ws_size < WS_NEEDED) {
    k_sentinel<<<1, 256, 0, stream>>>(out, 1.0e6f + (float)(ws_size >> 20));
    return;
  }

  _Float16* Wt1 = (_Float16*)(ws + OFF_WT1);
  _Float16* Wt2 = (_Float16*)(ws + OFF_WT2);
  _Float16* Xg = (_Float16*)(ws + OFF_XG);
  _Float16* Hbuf = (_Float16*)(ws + OFF_H);
  float* mixed = (float*)(ws + OFF_MIX);
  int* topi = (int*)(ws + OFF_TOPI);
  float* topg = (float*)(ws + OFF_TOPG);
  int* pair_token = (int*)(ws + OFF_PTOK);
  float* pair_gate = (float*)(ws + OFF_PGATE);
  int* hdr = (int*)(ws + OFF_HDR);
  int* cnt = hdr;
  float* imp = (float*)(hdr + 8);
  int* cursor = hdr + 16;

  hipMemsetAsync(hdr, 0, 64, stream);                              // cnt + imp
  hipMemsetAsync(mixed, 0, (size_t)N_TOK * DM * 4, stream);

  k_transpose<<<dim3(HID / 32, DM / 32, NE), 256, 0, stream>>>(W1, Wt1, DM, HID);
  k_transpose<<<dim3(DM / 32, HID / 32, NE), 256, 0, stream>>>(W2, Wt2, HID, DM);
  k_router<<<512, 256, 0, stream>>>(x, Wr, topi, topg, cnt, imp);
  k_setup<<<1, 1, 0, stream>>>(hdr, out + (size_t)N_TOK * DM);
  k_init_pairs<<<(MAX_SLOTS + 255) / 256, 256, 0, stream>>>(pair_token);
  k_scatter<<<N_TOK / 256, 256, 0, stream>>>(topi, topg, cursor, pair_token, pair_gate);
  k_gather<<<MAX_SLOTS, 256, 0, stream>>>(x, pair_token, Xg);
  k_gemm1<<<dim3(HID / 128, MAX_TILES), 256, 0, stream>>>(Xg, Wt1, b1, Hbuf, hdr);
  k_gemm2<<<dim3(DM / 128, MAX_TILES), 256, 0, stream>>>(Hbuf, Wt2, b2, pair_token, pair_gate, mixed, hdr);
  k_ln<<<N_TOK, 256, 0, stream>>>(x, mixed, lnw, lnb, out);
}

// Round 2
// 870.655 us; speedup vs baseline: 1.5988x; 1.5988x over previous
//
#include <hip/hip_runtime.h>

#define N_TOK 8192
#define DM 1024
#define HID 4096
#define NE 8
#define MAX_TILES 136
#define MAX_SLOTS (MAX_TILES * 128)
#define LN_EPS 1e-5f

typedef __attribute__((ext_vector_type(8))) _Float16 f16x8;
typedef __attribute__((ext_vector_type(4))) _Float16 f16x4;
typedef __attribute__((ext_vector_type(4))) float f32x4;

// ---------------- workspace layout ----------------
constexpr size_t OFF_WT1 = 0;                                       // [E][HID][DM] f16
constexpr size_t OFF_WT2 = OFF_WT1 + (size_t)NE * HID * DM * 2;     // [E][DM][HID] f16
constexpr size_t OFF_XG  = OFF_WT2 + (size_t)NE * DM * HID * 2;     // [MAX_SLOTS][DM] f16
constexpr size_t OFF_H   = OFF_XG + (size_t)MAX_SLOTS * DM * 2;     // [MAX_SLOTS][HID] f16
constexpr size_t OFF_Y   = OFF_H + (size_t)MAX_SLOTS * HID * 2;     // [MAX_SLOTS][DM] f16
constexpr size_t OFF_TOPI = OFF_Y + (size_t)MAX_SLOTS * DM * 2;     // [N_TOK][2] i32
constexpr size_t OFF_TOPG = OFF_TOPI + (size_t)N_TOK * 2 * 4;       // [N_TOK][2] f32
constexpr size_t OFF_PTOK = OFF_TOPG + (size_t)N_TOK * 2 * 4;       // [MAX_SLOTS] i32
constexpr size_t OFF_SLOT = OFF_PTOK + (size_t)MAX_SLOTS * 4;       // [N_TOK][2] i32
constexpr size_t OFF_HDR = OFF_SLOT + (size_t)N_TOK * 2 * 4;        // header
constexpr size_t WS_NEEDED = OFF_HDR + 4096;
// header: [0..7] cnt, [8..15] imp(float), [16..23] cursor, [24..32] off,
//         [33] n_tiles, [34..169] tile_expert

__device__ inline float gelu_tanh(float v) {
  float c = 0.7978845608028654f * (v + 0.044715f * v * v * v);
  return 0.5f * v * (1.0f + tanhf(c));
}

// async global->LDS, 16 B per lane. lds ptr must be wave-uniform.
__device__ inline void g2l16(const _Float16* g, _Float16* l) {
  __builtin_amdgcn_global_load_lds(
      (const __attribute__((address_space(1))) unsigned int*)g,
      (__attribute__((address_space(3))) unsigned int*)l, 16, 0, 0);
}

// ---------------- router: fp64 logits, top-2, softmax stats ----------------
__global__ __launch_bounds__(256) void k_router(
    const float* __restrict__ x, const float* __restrict__ Wr,
    int* __restrict__ topi, float* __restrict__ topg,
    int* __restrict__ cnt, float* __restrict__ imp) {
  __shared__ float wr[DM * NE];          // 32 KB
  __shared__ float blkImp[NE];
  __shared__ int blkCnt[NE];
  int tid = threadIdx.x;
  if (tid < NE) { blkImp[tid] = 0.0f; blkCnt[tid] = 0; }
  for (int i = tid; i < DM * NE / 4; i += 256)
    ((float4*)wr)[i] = ((const float4*)Wr)[i];
  __syncthreads();
  int wave = tid >> 6, lane = tid & 63;
  for (int it = 0; it < 4; ++it) {
    int t = blockIdx.x * 16 + wave * 4 + it;
    double acc[NE];
#pragma unroll
    for (int e = 0; e < NE; ++e) acc[e] = 0.0;
    for (int j = 0; j < DM / 64; ++j) {
      int d = j * 64 + lane;
      float xv = x[(size_t)t * DM + d];
#pragma unroll
      for (int e = 0; e < NE; ++e) acc[e] += (double)xv * (double)wr[d * NE + e];
    }
#pragma unroll
    for (int off = 32; off > 0; off >>= 1) {
#pragma unroll
      for (int e = 0; e < NE; ++e) acc[e] += __shfl_down(acc[e], off);
    }
    if (lane == 0) {
      int i0 = 0;
#pragma unroll
      for (int e = 1; e < NE; ++e) if (acc[e] > acc[i0]) i0 = e;
      int i1 = (i0 == 0) ? 1 : 0;
#pragma unroll
      for (int e = 0; e < NE; ++e) if (e != i0 && acc[e] > acc[i1]) i1 = e;
      double g0 = 1.0 / (1.0 + exp(acc[i1] - acc[i0]));
      topi[t * 2] = i0; topi[t * 2 + 1] = i1;
      topg[t * 2] = (float)g0; topg[t * 2 + 1] = (float)(1.0 - g0);
      atomicAdd(&blkCnt[i0], 1); atomicAdd(&blkCnt[i1], 1);
      double mx = acc[0];
#pragma unroll
      for (int e = 1; e < NE; ++e) mx = acc[e] > mx ? acc[e] : mx;
      double s = 0.0, p[NE];
#pragma unroll
      for (int e = 0; e < NE; ++e) { p[e] = exp(acc[e] - mx); s += p[e]; }
      double inv = 1.0 / s;
#pragma unroll
      for (int e = 0; e < NE; ++e) atomicAdd(&blkImp[e], (float)(p[e] * inv));
    }
  }
  __syncthreads();
  if (tid < NE) { atomicAdd(&cnt[tid], blkCnt[tid]); atomicAdd(&imp[tid], blkImp[tid]); }
}

// ---------------- setup: offsets (128-aligned), tile map, aux loss ----------------
__global__ void k_setup(int* __restrict__ hdr, float* __restrict__ aux_out) {
  int* cnt = hdr;
  float* imp = (float*)(hdr + 8);
  int* cursor = hdr + 16;
  int* off = hdr + 24;
  int* n_tiles_p = hdr + 33;
  int* tile_expert = hdr + 34;
  if (threadIdx.x == 0) {
    int offl[NE + 1];
    int o = 0;
    for (int e = 0; e < NE; ++e) {
      offl[e] = o; off[e] = o; cursor[e] = o;
      o += ((cnt[e] + 127) >> 7) << 7;
    }
    offl[NE] = o; off[NE] = o;
    int nt = o >> 7;
    *n_tiles_p = nt;
    int e = 0;
    for (int i = 0; i < nt; ++i) {
      while (i * 128 >= offl[e + 1]) ++e;
      tile_expert[i] = e;
    }
    double a = 0.0;
    for (int e2 = 0; e2 < NE; ++e2)
      a += ((double)imp[e2] / (double)N_TOK) * ((double)cnt[e2] / (double)N_TOK);
    *aux_out = (float)((double)NE * a);
  }
}

__global__ __launch_bounds__(256) void k_init_pairs(int* __restrict__ pair_token) {
  int i = blockIdx.x * 256 + threadIdx.x;
  if (i < MAX_SLOTS) pair_token[i] = -1;
}

// ---------------- scatter token->slot ----------------
__global__ __launch_bounds__(256) void k_scatter(
    const int* __restrict__ topi, int* __restrict__ cursor,
    int* __restrict__ pair_token, int* __restrict__ slot_of) {
  int t = blockIdx.x * 256 + threadIdx.x;
#pragma unroll
  for (int k = 0; k < 2; ++k) {
    int e = topi[t * 2 + k];
    int p = atomicAdd(&cursor[e], 1);
    pair_token[p] = t;
    slot_of[t * 2 + k] = p;
  }
}

// ---------------- gather x rows (fp32 -> f16) ----------------
__global__ __launch_bounds__(256) void k_gather(
    const float* __restrict__ x, const int* __restrict__ pair_token,
    _Float16* __restrict__ Xg) {
  int slot = blockIdx.x;
  int t = pair_token[slot];
  int d = threadIdx.x * 4;
  f16x4 v4 = {0, 0, 0, 0};
  if (t >= 0) {
    float4 v = *(const float4*)(x + (size_t)t * DM + d);
    v4[0] = (_Float16)v.x; v4[1] = (_Float16)v.y;
    v4[2] = (_Float16)v.z; v4[3] = (_Float16)v.w;
  }
  *(f16x4*)(Xg + (size_t)slot * DM + d) = v4;
}

// ---------------- transpose + cast weights: fp32 [R][C] -> f16 [C][R] ----------------
__global__ __launch_bounds__(256) void k_transpose(
    const float* __restrict__ in, _Float16* __restrict__ out, int R, int C) {
  __shared__ float tile[32][33];
  size_t base = (size_t)blockIdx.z * R * C;
  const float* src = in + base;
  _Float16* dst = out + base;
  int c0 = blockIdx.x * 32, r0 = blockIdx.y * 32;
  int tx = threadIdx.x & 31, ty = threadIdx.x >> 5;
#pragma unroll
  for (int i = 0; i < 32; i += 8)
    tile[ty + i][tx] = src[(size_t)(r0 + ty + i) * C + c0 + tx];
  __syncthreads();
#pragma unroll
  for (int i = 0; i < 32; i += 8)
    dst[(size_t)(c0 + ty + i) * R + r0 + tx] = (_Float16)tile[tx][ty + i];
}

// ---------------- async staging: 128 rows x 64 halves, XOR-swizzled ----------------
// slot s (16B chunk) = row*8 + (c ^ (row&7));  LDS tile = 16 KB, no padding.
__device__ inline void stage_async(const _Float16* __restrict__ g, int ld,
                                   _Float16* __restrict__ l, int tid) {
  int wbase = tid & 192;  // wave base (uniform per wave)
#pragma unroll
  for (int p = 0; p < 4; ++p) {
    int s = p * 256 + tid;
    int row = s >> 3;
    int c = (s & 7) ^ (row & 7);
    g2l16(g + (size_t)row * ld + c * 8, l + (size_t)(p * 256 + wbase) * 8);
  }
}

// swizzled fragment read: row stride 64 halves, chunk cc XOR row&7
__device__ inline f16x8 lds_frag(const _Float16* __restrict__ l, int row, int cc) {
  return *(const f16x8*)(l + row * 64 + (((cc) ^ (row & 7)) << 3));
}

// ---------------- GEMM1: H = gelu(Xg @ W1[e]^T + b1[e]) ----------------
__global__ __launch_bounds__(256, 4) void k_gemm1(
    const _Float16* __restrict__ Xg, const _Float16* __restrict__ Wt1,
    const float* __restrict__ b1, _Float16* __restrict__ H,
    const int* __restrict__ hdr) {
  int tileM = blockIdx.y;
  if (tileM >= hdr[33]) return;
  int e = hdr[34 + tileM];
  int tileN = blockIdx.x;
  __shared__ _Float16 Al[128 * 64];
  __shared__ _Float16 Bl[128 * 64];
  int tid = threadIdx.x;
  const _Float16* Ag = Xg + (size_t)tileM * 128 * DM;
  const _Float16* Bg = Wt1 + (size_t)e * HID * DM + (size_t)tileN * 128 * DM;
  f32x4 acc[4][4];
  const f32x4 fz = {0.f, 0.f, 0.f, 0.f};
#pragma unroll
  for (int a = 0; a < 4; ++a)
#pragma unroll
    for (int b = 0; b < 4; ++b) acc[a][b] = fz;
  int wave = tid >> 6, lane = tid & 63;
  int wm = wave & 1, wn = wave >> 1;
  int l16 = lane & 15, quad = lane >> 4;
  for (int k0 = 0; k0 < DM; k0 += 64) {
    stage_async(Ag + k0, DM, Al, tid);
    stage_async(Bg + k0, DM, Bl, tid);
    __syncthreads();
#pragma unroll
    for (int kk = 0; kk < 64; kk += 32) {
      f16x8 af[4], bfr[4];
      int cc = quad + (kk >> 3);
#pragma unroll
      for (int mi = 0; mi < 4; ++mi)
        af[mi] = lds_frag(Al, wm * 64 + mi * 16 + l16, cc);
#pragma unroll
      for (int ni = 0; ni < 4; ++ni)
        bfr[ni] = lds_frag(Bl, wn * 64 + ni * 16 + l16, cc);
#pragma unroll
      for (int mi = 0; mi < 4; ++mi)
#pragma unroll
        for (int ni = 0; ni < 4; ++ni)
          acc[mi][ni] = __builtin_amdgcn_mfma_f32_16x16x32_f16(af[mi], bfr[ni], acc[mi][ni], 0, 0, 0);
    }
    __syncthreads();
  }
  int rowBase = tileM * 128 + wm * 64;
  int colBase = tileN * 128 + wn * 64;
#pragma unroll
  for (int ni = 0; ni < 4; ++ni) {
    int col = colBase + ni * 16 + l16;
    float bv = b1[e * HID + col];
#pragma unroll
    for (int mi = 0; mi < 4; ++mi)
#pragma unroll
      for (int i = 0; i < 4; ++i) {
        int row = rowBase + mi * 16 + quad * 4 + i;
        float v = acc[mi][ni][i] + bv;
        H[(size_t)row * HID + col] = (_Float16)gelu_tanh(v);
      }
  }
}

// ---------------- GEMM2: Y[slot] = H @ W2[e]^T + b2[e]  (f16, ungated) ----------------
__global__ __launch_bounds__(256, 4) void k_gemm2(
    const _Float16* __restrict__ H, const _Float16* __restrict__ Wt2,
    const float* __restrict__ b2, _Float16* __restrict__ Y,
    const int* __restrict__ hdr) {
  int tileM = blockIdx.y;
  if (tileM >= hdr[33]) return;
  int e = hdr[34 + tileM];
  int tileN = blockIdx.x;
  __shared__ _Float16 Al[128 * 64];
  __shared__ _Float16 Bl[128 * 64];
  int tid = threadIdx.x;
  const _Float16* Ag = H + (size_t)tileM * 128 * HID;
  const _Float16* Bg = Wt2 + (size_t)e * DM * HID + (size_t)tileN * 128 * HID;
  f32x4 acc[4][4];
  const f32x4 fz = {0.f, 0.f, 0.f, 0.f};
#pragma unroll
  for (int a = 0; a < 4; ++a)
#pragma unroll
    for (int b = 0; b < 4; ++b) acc[a][b] = fz;
  int wave = tid >> 6, lane = tid & 63;
  int wm = wave & 1, wn = wave >> 1;
  int l16 = lane & 15, quad = lane >> 4;
  for (int k0 = 0; k0 < HID; k0 += 64) {
    stage_async(Ag + k0, HID, Al, tid);
    stage_async(Bg + k0, HID, Bl, tid);
    __syncthreads();
#pragma unroll
    for (int kk = 0; kk < 64; kk += 32) {
      f16x8 af[4], bfr[4];
      int cc = quad + (kk >> 3);
#pragma unroll
      for (int mi = 0; mi < 4; ++mi)
        af[mi] = lds_frag(Al, wm * 64 + mi * 16 + l16, cc);
#pragma unroll
      for (int ni = 0; ni < 4; ++ni)
        bfr[ni] = lds_frag(Bl, wn * 64 + ni * 16 + l16, cc);
#pragma unroll
      for (int mi = 0; mi < 4; ++mi)
#pragma unroll
        for (int ni = 0; ni < 4; ++ni)
          acc[mi][ni] = __builtin_amdgcn_mfma_f32_16x16x32_f16(af[mi], bfr[ni], acc[mi][ni], 0, 0, 0);
    }
    __syncthreads();
  }
  int rowBase = tileM * 128 + wm * 64;
  int colBase = tileN * 128 + wn * 64;
#pragma unroll
  for (int ni = 0; ni < 4; ++ni) {
    int col = colBase + ni * 16 + l16;
    float bv = b2[e * DM + col];
#pragma unroll
    for (int mi = 0; mi < 4; ++mi)
#pragma unroll
      for (int i = 0; i < 4; ++i) {
        int row = rowBase + mi * 16 + quad * 4 + i;
        Y[(size_t)row * DM + col] = (_Float16)(acc[mi][ni][i] + bv);
      }
  }
}

// ---------------- combine + residual + LayerNorm ----------------
__global__ __launch_bounds__(256) void k_ln(
    const float* __restrict__ x, const _Float16* __restrict__ Y,
    const int* __restrict__ slot_of, const float* __restrict__ topg,
    const float* __restrict__ lnw, const float* __restrict__ lnb,
    float* __restrict__ out) {
  int t = blockIdx.x, tid = threadIdx.x;
  int s0 = slot_of[t * 2], s1 = slot_of[t * 2 + 1];
  float g0 = topg[t * 2], g1 = topg[t * 2 + 1];
  float4 xv = ((const float4*)(x + (size_t)t * DM))[tid];
  f16x4 y0 = ((const f16x4*)(Y + (size_t)s0 * DM))[tid];
  f16x4 y1 = ((const f16x4*)(Y + (size_t)s1 * DM))[tid];
  float r0 = xv.x + g0 * (float)y0[0] + g1 * (float)y1[0];
  float r1 = xv.y + g0 * (float)y0[1] + g1 * (float)y1[1];
  float r2 = xv.z + g0 * (float)y0[2] + g1 * (float)y1[2];
  float r3 = xv.w + g0 * (float)y0[3] + g1 * (float)y1[3];
  float s = r0 + r1 + r2 + r3;
  float s2 = r0 * r0 + r1 * r1 + r2 * r2 + r3 * r3;
#pragma unroll
  for (int off = 32; off > 0; off >>= 1) {
    s += __shfl_down(s, off);
    s2 += __shfl_down(s2, off);
  }
  __shared__ float ss[4], ss2[4];
  int wave = tid >> 6, lane = tid & 63;
  if (lane == 0) { ss[wave] = s; ss2[wave] = s2; }
  __syncthreads();
  float S = ss[0] + ss[1] + ss[2] + ss[3];
  float S2 = ss2[0] + ss2[1] + ss2[2] + ss2[3];
  float mu = S * (1.0f / DM);
  float var = S2 * (1.0f / DM) - mu * mu;
  float inv = rsqrtf(var + LN_EPS);
  float4 wv = ((const float4*)lnw)[tid];
  float4 bv = ((const float4*)lnb)[tid];
  float4 o;
  o.x = (r0 - mu) * inv * wv.x + bv.x;
  o.y = (r1 - mu) * inv * wv.y + bv.y;
  o.z = (r2 - mu) * inv * wv.z + bv.z;
  o.w = (r3 - mu) * inv * wv.w + bv.w;
  ((float4*)(out + (size_t)t * DM))[tid] = o;
}

// sentinel: encodes ws_size (MB) into absmax if workspace is too small
__global__ void k_sentinel(float* out, float v) { out[threadIdx.x] = v; }

extern "C" void kernel_launch(void* const* d_in, const int* in_sizes, int n_in,
                              void* d_out, int out_size, void* d_ws, size_t ws_size,
                              hipStream_t stream) {
  const float* x = (const float*)d_in[0];
  const float* Wr = (const float*)d_in[1];
  const float* W1 = (const float*)d_in[2];
  const float* b1 = (const float*)d_in[3];
  const float* W2 = (const float*)d_in[4];
  const float* b2 = (const float*)d_in[5];
  const float* lnw = (const float*)d_in[6];
  const float* lnb = (const float*)d_in[7];
  float* out = (float*)d_out;
  char* ws = (char*)d_ws;

  if (ws_size < WS_NEEDED) {
    k_sentinel<<<1, 256, 0, stream>>>(out, 1.0e6f + (float)(ws_size >> 20));
    return;
  }

  _Float16* Wt1 = (_Float16*)(ws + OFF_WT1);
  _Float16* Wt2 = (_Float16*)(ws + OFF_WT2);
  _Float16* Xg = (_Float16*)(ws + OFF_XG);
  _Float16* Hbuf = (_Float16*)(ws + OFF_H);
  _Float16* Ybuf = (_Float16*)(ws + OFF_Y);
  int* topi = (int*)(ws + OFF_TOPI);
  float* topg = (float*)(ws + OFF_TOPG);
  int* pair_token = (int*)(ws + OFF_PTOK);
  int* slot_of = (int*)(ws + OFF_SLOT);
  int* hdr = (int*)(ws + OFF_HDR);
  int* cnt = hdr;
  float* imp = (float*)(hdr + 8);
  int* cursor = hdr + 16;

  hipMemsetAsync(hdr, 0, 64, stream);  // cnt + imp

  k_transpose<<<dim3(HID / 32, DM / 32, NE), 256, 0, stream>>>(W1, Wt1, DM, HID);
  k_transpose<<<dim3(DM / 32, HID / 32, NE), 256, 0, stream>>>(W2, Wt2, HID, DM);
  k_router<<<512, 256, 0, stream>>>(x, Wr, topi, topg, cnt, imp);
  k_setup<<<1, 1, 0, stream>>>(hdr, out + (size_t)N_TOK * DM);
  k_init_pairs<<<(MAX_SLOTS + 255) / 256, 256, 0, stream>>>(pair_token);
  k_scatter<<<N_TOK / 256, 256, 0, stream>>>(topi, cursor, pair_token, slot_of);
  k_gather<<<MAX_SLOTS, 256, 0, stream>>>(x, pair_token, Xg);
  k_gemm1<<<dim3(HID / 128, MAX_TILES), 256, 0, stream>>>(Xg, Wt1, b1, Hbuf, hdr);
  k_gemm2<<<dim3(DM / 128, MAX_TILES), 256, 0, stream>>>(Hbuf, Wt2, b2, Ybuf, hdr);
  k_ln<<<N_TOK, 256, 0, stream>>>(x, Ybuf, slot_of, topg, lnw, lnb, out);
}

// Round 3
// 841.926 us; speedup vs baseline: 1.6533x; 1.0341x over previous
//
#include <hip/hip_runtime.h>

#define N_TOK 8192
#define DM 1024
#define HID 4096
#define NE 8
#define MAX_TILES 136
#define MAX_SLOTS (MAX_TILES * 128)
#define LN_EPS 1e-5f

typedef __attribute__((ext_vector_type(8))) _Float16 f16x8;
typedef __attribute__((ext_vector_type(4))) _Float16 f16x4;
typedef __attribute__((ext_vector_type(4))) float f32x4;

// ---------------- workspace layout ----------------
constexpr size_t OFF_WT1 = 0;                                       // [E][HID][DM] f16
constexpr size_t OFF_WT2 = OFF_WT1 + (size_t)NE * HID * DM * 2;     // [E][DM][HID] f16
constexpr size_t OFF_XG  = OFF_WT2 + (size_t)NE * DM * HID * 2;     // [MAX_SLOTS][DM] f16
constexpr size_t OFF_H   = OFF_XG + (size_t)MAX_SLOTS * DM * 2;     // [MAX_SLOTS][HID] f16
constexpr size_t OFF_Y   = OFF_H + (size_t)MAX_SLOTS * HID * 2;     // [MAX_SLOTS][DM] f16
constexpr size_t OFF_TOPI = OFF_Y + (size_t)MAX_SLOTS * DM * 2;     // [N_TOK][2] i32
constexpr size_t OFF_TOPG = OFF_TOPI + (size_t)N_TOK * 2 * 4;       // [N_TOK][2] f32
constexpr size_t OFF_PTOK = OFF_TOPG + (size_t)N_TOK * 2 * 4;       // [MAX_SLOTS] i32
constexpr size_t OFF_SLOT = OFF_PTOK + (size_t)MAX_SLOTS * 4;       // [N_TOK][2] i32
constexpr size_t OFF_HDR = OFF_SLOT + (size_t)N_TOK * 2 * 4;        // header
constexpr size_t WS_NEEDED = OFF_HDR + 4096;
// header: [0..7] cnt, [8..15] imp(float), [16..23] cursor, [24..32] off,
//         [33] n_tiles, [34..169] tile_expert

// gelu(v) = 0.5 v (1 + tanh(c)) = v * sigmoid(2c),  c = 0.79788456(v + 0.044715 v^3)
__device__ inline float gelu_fast(float v) {
  float c = 0.7978845608028654f * (v + 0.044715f * v * v * v);
  return v / (1.0f + __expf(-2.0f * c));
}

// async global->LDS, 16 B per lane. lds ptr must be wave-uniform.
__device__ inline void g2l16(const _Float16* g, _Float16* l) {
  __builtin_amdgcn_global_load_lds(
      (const __attribute__((address_space(1))) unsigned int*)g,
      (__attribute__((address_space(3))) unsigned int*)l, 16, 0, 0);
}

// ---------------- router: fp64 logits, top-2, softmax stats ----------------
__global__ __launch_bounds__(256) void k_router(
    const float* __restrict__ x, const float* __restrict__ Wr,
    int* __restrict__ topi, float* __restrict__ topg,
    int* __restrict__ cnt, float* __restrict__ imp) {
  __shared__ float wr[DM * NE];          // 32 KB
  __shared__ float blkImp[NE];
  __shared__ int blkCnt[NE];
  int tid = threadIdx.x;
  if (tid < NE) { blkImp[tid] = 0.0f; blkCnt[tid] = 0; }
  for (int i = tid; i < DM * NE / 4; i += 256)
    ((float4*)wr)[i] = ((const float4*)Wr)[i];
  __syncthreads();
  int wave = tid >> 6, lane = tid & 63;
  for (int it = 0; it < 4; ++it) {
    int t = blockIdx.x * 16 + wave * 4 + it;
    double acc[NE];
#pragma unroll
    for (int e = 0; e < NE; ++e) acc[e] = 0.0;
    for (int j = 0; j < DM / 64; ++j) {
      int d = j * 64 + lane;
      float xv = x[(size_t)t * DM + d];
#pragma unroll
      for (int e = 0; e < NE; ++e) acc[e] += (double)xv * (double)wr[d * NE + e];
    }
#pragma unroll
    for (int off = 32; off > 0; off >>= 1) {
#pragma unroll
      for (int e = 0; e < NE; ++e) acc[e] += __shfl_down(acc[e], off);
    }
    if (lane == 0) {
      int i0 = 0;
#pragma unroll
      for (int e = 1; e < NE; ++e) if (acc[e] > acc[i0]) i0 = e;
      int i1 = (i0 == 0) ? 1 : 0;
#pragma unroll
      for (int e = 0; e < NE; ++e) if (e != i0 && acc[e] > acc[i1]) i1 = e;
      double g0 = 1.0 / (1.0 + exp(acc[i1] - acc[i0]));
      topi[t * 2] = i0; topi[t * 2 + 1] = i1;
      topg[t * 2] = (float)g0; topg[t * 2 + 1] = (float)(1.0 - g0);
      atomicAdd(&blkCnt[i0], 1); atomicAdd(&blkCnt[i1], 1);
      double mx = acc[0];
#pragma unroll
      for (int e = 1; e < NE; ++e) mx = acc[e] > mx ? acc[e] : mx;
      double s = 0.0, p[NE];
#pragma unroll
      for (int e = 0; e < NE; ++e) { p[e] = exp(acc[e] - mx); s += p[e]; }
      double inv = 1.0 / s;
#pragma unroll
      for (int e = 0; e < NE; ++e) atomicAdd(&blkImp[e], (float)(p[e] * inv));
    }
  }
  __syncthreads();
  if (tid < NE) { atomicAdd(&cnt[tid], blkCnt[tid]); atomicAdd(&imp[tid], blkImp[tid]); }
}

// ---------------- setup: offsets (128-aligned), tile map, aux loss ----------------
__global__ void k_setup(int* __restrict__ hdr, float* __restrict__ aux_out) {
  int* cnt = hdr;
  float* imp = (float*)(hdr + 8);
  int* cursor = hdr + 16;
  int* off = hdr + 24;
  int* n_tiles_p = hdr + 33;
  int* tile_expert = hdr + 34;
  if (threadIdx.x == 0) {
    int offl[NE + 1];
    int o = 0;
    for (int e = 0; e < NE; ++e) {
      offl[e] = o; off[e] = o; cursor[e] = o;
      o += ((cnt[e] + 127) >> 7) << 7;
    }
    offl[NE] = o; off[NE] = o;
    int nt = o >> 7;
    *n_tiles_p = nt;
    int e = 0;
    for (int i = 0; i < nt; ++i) {
      while (i * 128 >= offl[e + 1]) ++e;
      tile_expert[i] = e;
    }
    double a = 0.0;
    for (int e2 = 0; e2 < NE; ++e2)
      a += ((double)imp[e2] / (double)N_TOK) * ((double)cnt[e2] / (double)N_TOK);
    *aux_out = (float)((double)NE * a);
  }
}

__global__ __launch_bounds__(256) void k_init_pairs(int* __restrict__ pair_token) {
  int i = blockIdx.x * 256 + threadIdx.x;
  if (i < MAX_SLOTS) pair_token[i] = -1;
}

// ---------------- scatter token->slot ----------------
__global__ __launch_bounds__(256) void k_scatter(
    const int* __restrict__ topi, int* __restrict__ cursor,
    int* __restrict__ pair_token, int* __restrict__ slot_of) {
  int t = blockIdx.x * 256 + threadIdx.x;
#pragma unroll
  for (int k = 0; k < 2; ++k) {
    int e = topi[t * 2 + k];
    int p = atomicAdd(&cursor[e], 1);
    pair_token[p] = t;
    slot_of[t * 2 + k] = p;
  }
}

// ---------------- gather x rows (fp32 -> f16) ----------------
__global__ __launch_bounds__(256) void k_gather(
    const float* __restrict__ x, const int* __restrict__ pair_token,
    _Float16* __restrict__ Xg) {
  int slot = blockIdx.x;
  int t = pair_token[slot];
  int d = threadIdx.x * 4;
  f16x4 v4 = {0, 0, 0, 0};
  if (t >= 0) {
    float4 v = *(const float4*)(x + (size_t)t * DM + d);
    v4[0] = (_Float16)v.x; v4[1] = (_Float16)v.y;
    v4[2] = (_Float16)v.z; v4[3] = (_Float16)v.w;
  }
  *(f16x4*)(Xg + (size_t)slot * DM + d) = v4;
}

// ---------------- transpose + cast: fp32 [R][C] -> f16 [C][R], 64x64 tiles ----------------
__global__ __launch_bounds__(256) void k_transpose(
    const float* __restrict__ in, _Float16* __restrict__ out, int R, int C) {
  __shared__ float t[64 * 65];
  size_t base = (size_t)blockIdx.z * R * C;
  int c0 = blockIdx.x * 64, r0 = blockIdx.y * 64;
  int cx = (threadIdx.x & 15) * 4, ry = threadIdx.x >> 4;
#pragma unroll
  for (int p = 0; p < 4; ++p) {
    int r = p * 16 + ry;
    float4 v = *(const float4*)(in + base + (size_t)(r0 + r) * C + c0 + cx);
    t[r * 65 + cx] = v.x; t[r * 65 + cx + 1] = v.y;
    t[r * 65 + cx + 2] = v.z; t[r * 65 + cx + 3] = v.w;
  }
  __syncthreads();
#pragma unroll
  for (int q = 0; q < 2; ++q) {
    int lin = q * 256 + threadIdx.x;
    int c = lin >> 3, ch = lin & 7;
    f16x8 v;
#pragma unroll
    for (int j = 0; j < 8; ++j) v[j] = (_Float16)t[(ch * 8 + j) * 65 + c];
    *(f16x8*)(out + base + (size_t)(c0 + c) * R + r0 + ch * 8) = v;
  }
}

// ---------------- async staging: 128 rows x 64 halves, XOR-swizzled ----------------
__device__ inline void stage_async(const _Float16* __restrict__ g, int ld,
                                   _Float16* __restrict__ l, int tid) {
  int wbase = tid & 192;  // wave base (uniform per wave)
#pragma unroll
  for (int p = 0; p < 4; ++p) {
    int s = p * 256 + tid;
    int row = s >> 3;
    int c = (s & 7) ^ (row & 7);
    g2l16(g + (size_t)row * ld + c * 8, l + (size_t)(p * 256 + wbase) * 8);
  }
}

// swizzled fragment read: row stride 64 halves, chunk cc XOR row&7
__device__ inline f16x8 lds_frag(const _Float16* __restrict__ l, int row, int cc) {
  return *(const f16x8*)(l + row * 64 + (((cc) ^ (row & 7)) << 3));
}

// ---------------- GEMM1: H = gelu(Xg @ W1[e]^T + b1[e]) ----------------
__global__ __launch_bounds__(256, 4) void k_gemm1(
    const _Float16* __restrict__ Xg, const _Float16* __restrict__ Wt1,
    const float* __restrict__ b1, _Float16* __restrict__ H,
    const int* __restrict__ hdr) {
  int tileM = blockIdx.y;
  if (tileM >= hdr[33]) return;
  int e = hdr[34 + tileM];
  int tileN = blockIdx.x;
  __shared__ _Float16 lds[2 * 128 * 64];  // 32 KB: Al | Bl, reused as epilogue scratch
  _Float16* Al = lds;
  _Float16* Bl = lds + 128 * 64;
  int tid = threadIdx.x;
  const _Float16* Ag = Xg + (size_t)tileM * 128 * DM;
  const _Float16* Bg = Wt1 + (size_t)e * HID * DM + (size_t)tileN * 128 * DM;
  f32x4 acc[4][4];
  const f32x4 fz = {0.f, 0.f, 0.f, 0.f};
#pragma unroll
  for (int a = 0; a < 4; ++a)
#pragma unroll
    for (int b = 0; b < 4; ++b) acc[a][b] = fz;
  int wave = tid >> 6, lane = tid & 63;
  int wm = wave & 1, wn = wave >> 1;
  int l16 = lane & 15, quad = lane >> 4;
  for (int k0 = 0; k0 < DM; k0 += 64) {
    stage_async(Ag + k0, DM, Al, tid);
    stage_async(Bg + k0, DM, Bl, tid);
    __syncthreads();
#pragma unroll
    for (int kk = 0; kk < 64; kk += 32) {
      f16x8 af[4], bfr[4];
      int cc = quad + (kk >> 3);
#pragma unroll
      for (int mi = 0; mi < 4; ++mi)
        af[mi] = lds_frag(Al, wm * 64 + mi * 16 + l16, cc);
#pragma unroll
      for (int ni = 0; ni < 4; ++ni)
        bfr[ni] = lds_frag(Bl, wn * 64 + ni * 16 + l16, cc);
#pragma unroll
      for (int mi = 0; mi < 4; ++mi)
#pragma unroll
        for (int ni = 0; ni < 4; ++ni)
          acc[mi][ni] = __builtin_amdgcn_mfma_f32_16x16x32_f16(af[mi], bfr[ni], acc[mi][ni], 0, 0, 0);
    }
    __syncthreads();
  }
  // epilogue: bias + gelu -> per-wave LDS scratch -> coalesced f16x8 stores
  int rowBase = tileM * 128 + wm * 64;
  int colBase = tileN * 128 + wn * 64;
  _Float16* sc = lds + wave * 4096;  // 8 KB per wave
  float bv[4];
#pragma unroll
  for (int ni = 0; ni < 4; ++ni) bv[ni] = b1[e * HID + colBase + ni * 16 + l16];
#pragma unroll
  for (int mi = 0; mi < 4; ++mi)
#pragma unroll
    for (int ni = 0; ni < 4; ++ni)
#pragma unroll
      for (int i = 0; i < 4; ++i) {
        int r = mi * 16 + quad * 4 + i;
        int c = ni * 16 + l16;
        sc[r * 64 + c] = (_Float16)gelu_fast(acc[mi][ni][i] + bv[ni]);
      }
  __syncthreads();
#pragma unroll
  for (int j = 0; j < 8; ++j) {
    int lin = j * 64 + lane;
    int r = lin >> 3, ch = lin & 7;
    f16x8 v = *(const f16x8*)(sc + r * 64 + ch * 8);
    *(f16x8*)(H + (size_t)(rowBase + r) * HID + colBase + ch * 8) = v;
  }
}

// ---------------- GEMM2: Y[slot] = H @ W2[e]^T + b2[e]  (f16, ungated) ----------------
__global__ __launch_bounds__(256, 4) void k_gemm2(
    const _Float16* __restrict__ H, const _Float16* __restrict__ Wt2,
    const float* __restrict__ b2, _Float16* __restrict__ Y,
    const int* __restrict__ hdr) {
  int tileM = blockIdx.y;
  if (tileM >= hdr[33]) return;
  int e = hdr[34 + tileM];
  int tileN = blockIdx.x;
  __shared__ _Float16 lds[2 * 128 * 64];
  _Float16* Al = lds;
  _Float16* Bl = lds + 128 * 64;
  int tid = threadIdx.x;
  const _Float16* Ag = H + (size_t)tileM * 128 * HID;
  const _Float16* Bg = Wt2 + (size_t)e * DM * HID + (size_t)tileN * 128 * HID;
  f32x4 acc[4][4];
  const f32x4 fz = {0.f, 0.f, 0.f, 0.f};
#pragma unroll
  for (int a = 0; a < 4; ++a)
#pragma unroll
    for (int b = 0; b < 4; ++b) acc[a][b] = fz;
  int wave = tid >> 6, lane = tid & 63;
  int wm = wave & 1, wn = wave >> 1;
  int l16 = lane & 15, quad = lane >> 4;
  for (int k0 = 0; k0 < HID; k0 += 64) {
    stage_async(Ag + k0, HID, Al, tid);
    stage_async(Bg + k0, HID, Bl, tid);
    __syncthreads();
#pragma unroll
    for (int kk = 0; kk < 64; kk += 32) {
      f16x8 af[4], bfr[4];
      int cc = quad + (kk >> 3);
#pragma unroll
      for (int mi = 0; mi < 4; ++mi)
        af[mi] = lds_frag(Al, wm * 64 + mi * 16 + l16, cc);
#pragma unroll
      for (int ni = 0; ni < 4; ++ni)
        bfr[ni] = lds_frag(Bl, wn * 64 + ni * 16 + l16, cc);
#pragma unroll
      for (int mi = 0; mi < 4; ++mi)
#pragma unroll
        for (int ni = 0; ni < 4; ++ni)
          acc[mi][ni] = __builtin_amdgcn_mfma_f32_16x16x32_f16(af[mi], bfr[ni], acc[mi][ni], 0, 0, 0);
    }
    __syncthreads();
  }
  int rowBase = tileM * 128 + wm * 64;
  int colBase = tileN * 128 + wn * 64;
  _Float16* sc = lds + wave * 4096;
  float bv[4];
#pragma unroll
  for (int ni = 0; ni < 4; ++ni) bv[ni] = b2[e * DM + colBase + ni * 16 + l16];
#pragma unroll
  for (int mi = 0; mi < 4; ++mi)
#pragma unroll
    for (int ni = 0; ni < 4; ++ni)
#pragma unroll
      for (int i = 0; i < 4; ++i) {
        int r = mi * 16 + quad * 4 + i;
        int c = ni * 16 + l16;
        sc[r * 64 + c] = (_Float16)(acc[mi][ni][i] + bv[ni]);
      }
  __syncthreads();
#pragma unroll
  for (int j = 0; j < 8; ++j) {
    int lin = j * 64 + lane;
    int r = lin >> 3, ch = lin & 7;
    f16x8 v = *(const f16x8*)(sc + r * 64 + ch * 8);
    *(f16x8*)(Y + (size_t)(rowBase + r) * DM + colBase + ch * 8) = v;
  }
}

// ---------------- combine + residual + LayerNorm ----------------
__global__ __launch_bounds__(256) void k_ln(
    const float* __restrict__ x, const _Float16* __restrict__ Y,
    const int* __restrict__ slot_of, const float* __restrict__ topg,
    const float* __restrict__ lnw, const float* __restrict__ lnb,
    float* __restrict__ out) {
  int t = blockIdx.x, tid = threadIdx.x;
  int s0 = slot_of[t * 2], s1 = slot_of[t * 2 + 1];
  float g0 = topg[t * 2], g1 = topg[t * 2 + 1];
  float4 xv = ((const float4*)(x + (size_t)t * DM))[tid];
  f16x4 y0 = ((const f16x4*)(Y + (size_t)s0 * DM))[tid];
  f16x4 y1 = ((const f16x4*)(Y + (size_t)s1 * DM))[tid];
  float r0 = xv.x + g0 * (float)y0[0] + g1 * (float)y1[0];
  float r1 = xv.y + g0 * (float)y0[1] + g1 * (float)y1[1];
  float r2 = xv.z + g0 * (float)y0[2] + g1 * (float)y1[2];
  float r3 = xv.w + g0 * (float)y0[3] + g1 * (float)y1[3];
  float s = r0 + r1 + r2 + r3;
  float s2 = r0 * r0 + r1 * r1 + r2 * r2 + r3 * r3;
#pragma unroll
  for (int off = 32; off > 0; off >>= 1) {
    s += __shfl_down(s, off);
    s2 += __shfl_down(s2, off);
  }
  __shared__ float ss[4], ss2[4];
  int wave = tid >> 6, lane = tid & 63;
  if (lane == 0) { ss[wave] = s; ss2[wave] = s2; }
  __syncthreads();
  float S = ss[0] + ss[1] + ss[2] + ss[3];
  float S2 = ss2[0] + ss2[1] + ss2[2] + ss2[3];
  float mu = S * (1.0f / DM);
  float var = S2 * (1.0f / DM) - mu * mu;
  float inv = rsqrtf(var + LN_EPS);
  float4 wv = ((const float4*)lnw)[tid];
  float4 bv = ((const float4*)lnb)[tid];
  float4 o;
  o.x = (r0 - mu) * inv * wv.x + bv.x;
  o.y = (r1 - mu) * inv * wv.y + bv.y;
  o.z = (r2 - mu) * inv * wv.z + bv.z;
  o.w = (r3 - mu) * inv * wv.w + bv.w;
  ((float4*)(out + (size_t)t * DM))[tid] = o;
}

// sentinel: encodes ws_size (MB) into absmax if workspace is too small
__global__ void k_sentinel(float* out, float v) { out[threadIdx.x] = v; }

extern "C" void kernel_launch(void* const* d_in, const int* in_sizes, int n_in,
                              void* d_out, int out_size, void* d_ws, size_t ws_size,
                              hipStream_t stream) {
  const float* x = (const float*)d_in[0];
  const float* Wr = (const float*)d_in[1];
  const float* W1 = (const float*)d_in[2];
  const float* b1 = (const float*)d_in[3];
  const float* W2 = (const float*)d_in[4];
  const float* b2 = (const float*)d_in[5];
  const float* lnw = (const float*)d_in[6];
  const float* lnb = (const float*)d_in[7];
  float* out = (float*)d_out;
  char* ws = (char*)d_ws;

  if (ws_size < WS_NEEDED) {
    k_sentinel<<<1, 256, 0, stream>>>(out, 1.0e6f + (float)(ws_size >> 20));
    return;
  }

  _Float16* Wt1 = (_Float16*)(ws + OFF_WT1);
  _Float16* Wt2 = (_Float16*)(ws + OFF_WT2);
  _Float16* Xg = (_Float16*)(ws + OFF_XG);
  _Float16* Hbuf = (_Float16*)(ws + OFF_H);
  _Float16* Ybuf = (_Float16*)(ws + OFF_Y);
  int* topi = (int*)(ws + OFF_TOPI);
  float* topg = (float*)(ws + OFF_TOPG);
  int* pair_token = (int*)(ws + OFF_PTOK);
  int* slot_of = (int*)(ws + OFF_SLOT);
  int* hdr = (int*)(ws + OFF_HDR);
  int* cnt = hdr;
  float* imp = (float*)(hdr + 8);
  int* cursor = hdr + 16;

  hipMemsetAsync(hdr, 0, 64, stream);  // cnt + imp

  k_transpose<<<dim3(HID / 64, DM / 64, NE), 256, 0, stream>>>(W1, Wt1, DM, HID);
  k_transpose<<<dim3(DM / 64, HID / 64, NE), 256, 0, stream>>>(W2, Wt2, HID, DM);
  k_router<<<512, 256, 0, stream>>>(x, Wr, topi, topg, cnt, imp);
  k_setup<<<1, 1, 0, stream>>>(hdr, out + (size_t)N_TOK * DM);
  k_init_pairs<<<(MAX_SLOTS + 255) / 256, 256, 0, stream>>>(pair_token);
  k_scatter<<<N_TOK / 256, 256, 0, stream>>>(topi, cursor, pair_token, slot_of);
  k_gather<<<MAX_SLOTS, 256, 0, stream>>>(x, pair_token, Xg);
  k_gemm1<<<dim3(HID / 128, MAX_TILES), 256, 0, stream>>>(Xg, Wt1, b1, Hbuf, hdr);
  k_gemm2<<<dim3(DM / 128, MAX_TILES), 256, 0, stream>>>(Hbuf, Wt2, b2, Ybuf, hdr);
  k_ln<<<N_TOK, 256, 0, stream>>>(x, Ybuf, slot_of, topg, lnw, lnb, out);
}